// Round 8
// baseline (271.815 us; speedup 1.0000x reference)
//
#include <hip/hip_runtime.h>
#include <limits.h>
#include <math.h>
#include <stdint.h>

// Problem constants (fixed by setup_inputs): x[128][262144] fp32, topk=5.
#define BROWS 128
#define NCOLS (256 * 32 * 32)        // 262144 elements per row
#define K 5
#define BPR 16                       // filter blocks per row -> 2048 blocks
#define TPB 256
#define CHUNK (NCOLS / BPR)          // 16384 elements per block
#define F4T (CHUNK / 4 / TPB)        // 16 float4 per thread
#define CAP 1024                     // per-row candidate capacity

// Fixed filter threshold. x ~ N(0,1): P(Z>=3.3)=4.83e-4 -> ~127 survivors/row
// (sigma ~11), row top-5 is at z~4.2. Underflow (<5) or overflow (>CAP) are
// each >10 sigma out AND handled exactly by wta_fallback, so this is
// input-robust: cnt>=5 implies row's 5th-largest >= T implies all top-5 are
// in the candidate list; otherwise the row is recomputed exactly.
#define T_FILTER 3.3f

typedef float v4f __attribute__((ext_vector_type(4)));

// ---- packed 64-bit candidate key: [sortable_f32 : 32][~index : 32] ----
// bigger key == better (value desc, then index asc) -> matches jax.lax.top_k.
__device__ __forceinline__ uint64_t make_key(float f, uint32_t idx) {
    uint32_t u = __float_as_uint(f);
    u = (u & 0x80000000u) ? ~u : (u | 0x80000000u);   // monotone fp32 -> u32
    return ((uint64_t)u << 32) | (uint32_t)(~idx);
}
__device__ __forceinline__ float key_val(uint64_t k) {
    uint32_t u = (uint32_t)(k >> 32);
    u = (u & 0x80000000u) ? (u ^ 0x80000000u) : ~u;
    return __uint_as_float(u);
}
__device__ __forceinline__ uint32_t key_idx(uint64_t k) { return ~(uint32_t)k; }

// Sentinel decodes to exactly -inf via key_val (key==0 decodes to NaN).
#define KEY_NEG_INF 0x007FFFFF00000000ULL  // make_key(-INFINITY, 0xFFFFFFFF)

__device__ __forceinline__ void insert5(uint64_t (&key)[K], uint64_t c) {
    if (c > key[K - 1]) {
        key[K - 1] = c;
#pragma unroll
        for (int s = K - 1; s > 0; --s) {
            if (key[s] > key[s - 1]) {
                uint64_t t = key[s]; key[s] = key[s - 1]; key[s - 1] = t;
            }
        }
    }
}

__device__ __forceinline__ void wave_reduce5(uint64_t (&key)[K]) {
#pragma unroll
    for (int off = 1; off < 64; off <<= 1) {
        uint64_t ok[K];
#pragma unroll
        for (int k = 0; k < K; ++k)
            ok[k] = __shfl_xor((unsigned long long)key[k], off, 64);
#pragma unroll
        for (int k = 0; k < K; ++k) insert5(key, ok[k]);
    }
}

// K0: zero the per-row atomic counters (d_ws is poisoned 0xAA every launch).
__global__ void wta_zerocnt(int* __restrict__ cnt) {
    if (threadIdx.x < BROWS) cnt[threadIdx.x] = 0;
}

// K1: the only full-traffic pass. Fused nt-zero-fill + fixed-threshold filter.
// Guard compares against a compile-time constant -> no loop-carried dep; the
// wave fast path is real (survivor rate ~5e-4).
__global__ __launch_bounds__(TPB) void wta_fillfilter(const float* __restrict__ x,
                                                      float* __restrict__ out,
                                                      int* __restrict__ cnt,
                                                      uint64_t* __restrict__ cand) {
    const int gb  = blockIdx.x;
    const int row = gb / BPR;
    const int blk = gb % BPR;
    const size_t base = (size_t)gb * CHUNK;
    const float4* __restrict__ x4 = (const float4*)(x + base);
    v4f* __restrict__ o4 = (v4f*)(out + base);
    const int t = threadIdx.x;
    const v4f z = {0.f, 0.f, 0.f, 0.f};

#pragma unroll
    for (int h = 0; h < 2; ++h) {   // two half-batches of 8 for bounded VGPRs
        float4 r[F4T / 2];
#pragma unroll
        for (int j = 0; j < F4T / 2; ++j)
            r[j] = x4[t + (h * (F4T / 2) + j) * TPB];
#pragma unroll
        for (int j = 0; j < F4T / 2; ++j)
            __builtin_nontemporal_store(z, &o4[t + (h * (F4T / 2) + j) * TPB]);
#pragma unroll
        for (int j = 0; j < F4T / 2; ++j) {
            const float4 d = r[j];
            const float m = fmaxf(fmaxf(d.x, d.y), fmaxf(d.z, d.w));
            if (m >= T_FILTER) {    // rare: ~127 hits per 262144 elements
                const uint32_t e = (uint32_t)blk * CHUNK +
                                   (uint32_t)(t + (h * (F4T / 2) + j) * TPB) * 4u;
                const float vs[4] = {d.x, d.y, d.z, d.w};
#pragma unroll
                for (int c = 0; c < 4; ++c) {
                    if (vs[c] >= T_FILTER) {
                        const int slot = atomicAdd(&cnt[row], 1);
                        if (slot < CAP) cand[row * CAP + slot] = make_key(vs[c], e + c);
                    }
                }
            }
        }
    }
}

// K2: exact per-row fallback; uniform early-exit when the filter succeeded
// (5 <= cnt <= CAP). Never runs for N(0,1) input, guarantees correctness
// for any input.
__global__ __launch_bounds__(TPB) void wta_fallback(const float* __restrict__ x,
                                                    int* __restrict__ cnt,
                                                    uint64_t* __restrict__ cand) {
    const int row = blockIdx.x;
    const int n = cnt[row];                 // uniform across the block
    if (n >= K && n <= CAP) return;

    const float4* __restrict__ x4 = (const float4*)(x + (size_t)row * NCOLS);
    const int t = threadIdx.x;

    uint64_t key[K];
#pragma unroll
    for (int k = 0; k < K; ++k) key[k] = KEY_NEG_INF;
    float vmin = -INFINITY;

    for (int i = t; i < NCOLS / 4; i += TPB) {
        const float4 d = x4[i];
        const float m = fmaxf(fmaxf(d.x, d.y), fmaxf(d.z, d.w));
        if (m >= vmin) {
            const uint32_t e = (uint32_t)i * 4u;
            insert5(key, make_key(d.x, e + 0));
            insert5(key, make_key(d.y, e + 1));
            insert5(key, make_key(d.z, e + 2));
            insert5(key, make_key(d.w, e + 3));
            vmin = key_val(key[K - 1]);
        }
    }

    wave_reduce5(key);

    __shared__ uint64_t sk[TPB / 64][K];
    const int wave = t >> 6, lane = t & 63;
    if (lane == 0) {
#pragma unroll
        for (int k = 0; k < K; ++k) sk[wave][k] = key[k];
    }
    __syncthreads();
    if (t == 0) {
#pragma unroll
        for (int w = 1; w < TPB / 64; ++w)
#pragma unroll
            for (int k = 0; k < K; ++k) insert5(key, sk[w][k]);
#pragma unroll
        for (int k = 0; k < K; ++k) cand[row * CAP + k] = key[k];
        cnt[row] = K;                       // exact top-5 now in cand
    }
}

// K3: per row, top-5 of the survivors, scatter five 1.0f stores.
__global__ __launch_bounds__(64) void wta_final(const int* __restrict__ cnt,
                                                const uint64_t* __restrict__ cand,
                                                float* __restrict__ out) {
    const int row = blockIdx.x, lane = threadIdx.x;
    const int n = min(cnt[row], CAP);

    uint64_t key[K];
#pragma unroll
    for (int k = 0; k < K; ++k) key[k] = KEY_NEG_INF;
    for (int c = lane; c < n; c += 64) insert5(key, cand[row * CAP + c]);

    wave_reduce5(key);

    if (lane == 0) {
#pragma unroll
        for (int k = 0; k < K; ++k)
            if (key[k] != KEY_NEG_INF)
                out[(size_t)row * NCOLS + key_idx(key[k])] = 1.0f;
    }
}

extern "C" void kernel_launch(void* const* d_in, const int* in_sizes, int n_in,
                              void* d_out, int out_size, void* d_ws, size_t ws_size,
                              hipStream_t stream) {
    const float* x = (const float*)d_in[0];
    float* out = (float*)d_out;

    // ws layout: cand (128*1024 u64 = 1 MiB) | cnt (128 i32)
    uint64_t* cand = (uint64_t*)d_ws;
    int* cnt = (int*)(cand + (size_t)BROWS * CAP);

    wta_zerocnt<<<1, 128, 0, stream>>>(cnt);
    wta_fillfilter<<<BROWS * BPR, TPB, 0, stream>>>(x, out, cnt, cand);
    wta_fallback<<<BROWS, TPB, 0, stream>>>(x, cnt, cand);
    wta_final<<<BROWS, 64, 0, stream>>>(cnt, cand, out);
}